// Round 3
// baseline (370.953 us; speedup 1.0000x reference)
//
#include <hip/hip_runtime.h>
#include <math.h>

#define TLEN  8192
#define BROWS 4096
#define SEG   1024
#define NSEG  8                 /* TLEN / SEG */
#define NBLK  (BROWS * NSEG)    /* 32768 */
#define NT    256
#define CH    4                 /* SEG / NT */
#define GAMMA 0.99f
#define EPSN  1e-9

// ---------------------------------------------------------------------------
// K_A: per-segment summaries. Block = one 1024-elem segment; thread owns 4
// consecutive elems (one float4 per input -> fully coalesced). Emits the
// segment affine composite (A,P) and 5 moment sums so that, for any incoming
// carry c:  sum(ret) = Sa + Sp*c,  sum(ret^2) = Saa + 2c*Sap + c^2*Spp.
// ---------------------------------------------------------------------------
__global__ __launch_bounds__(NT) void er_segA(const float* __restrict__ rew,
                                              const float* __restrict__ don,
                                              float* __restrict__ fA,  float* __restrict__ fP,
                                              float* __restrict__ fSa, float* __restrict__ fSp,
                                              float* __restrict__ fSaa,float* __restrict__ fSap,
                                              float* __restrict__ fSpp) {
  const int blk  = blockIdx.x;
  const int tid  = threadIdx.x;
  const int lane = tid & 63, wv = tid >> 6;
  const size_t base = (size_t)blk * SEG + (size_t)tid * CH;

  const float4 rv = *(const float4*)(rew + base);
  const float4 dv = *(const float4*)(don + base);

  // thread-local suffix scan: a[j],p[j] = affine composite of [j, chunk end)
  float a[CH], p[CH];
  float A = 0.f, P = 1.f;
  {
    const float r[CH] = {rv.x, rv.y, rv.z, rv.w};
    const float d[CH] = {dv.x, dv.y, dv.z, dv.w};
#pragma unroll
    for (int j = CH - 1; j >= 0; --j) {
      const float c = GAMMA - GAMMA * d[j];
      A = fmaf(c, A, r[j]);
      P *= c;
      a[j] = A; p[j] = P;
    }
  }
  float sa = 0.f, sp = 0.f, saa = 0.f, sap = 0.f, spp = 0.f;
#pragma unroll
  for (int j = 0; j < CH; ++j) {
    sa += a[j]; sp += p[j];
    saa = fmaf(a[j], a[j], saa);
    sap = fmaf(a[j], p[j], sap);
    spp = fmaf(p[j], p[j], spp);
  }

  // wave inclusive suffix scan of (A,P)
  float sA = A, sP = P;
#pragma unroll
  for (int d = 1; d < 64; d <<= 1) {
    const float tA = __shfl_down(sA, d);
    const float tP = __shfl_down(sP, d);
    if (lane + d < 64) { sA = fmaf(sP, tA, sA); sP *= tP; }
  }
  __shared__ float wgA[4], wgP[4];
  __shared__ float red[20];
  if (lane == 0) { wgA[wv] = sA; wgP[wv] = sP; }
  __syncthreads();

  // affine composite of waves (wv,3] : x -> vA + vP*x
  float vA = 0.f, vP = 1.f;
#pragma unroll
  for (int j = 3; j >= 1; --j) {
    const float nA = fmaf(wgP[j], vA, wgA[j]);
    const float nP = vP * wgP[j];
    if (j > wv) { vA = nA; vP = nP; }
  }
  // exclusive-within-wave composite (lanes above), then compose with wave carry
  float eA = __shfl_down(sA, 1);
  float eP = __shfl_down(sP, 1);
  if (lane == 63) { eA = 0.f; eP = 1.f; }
  const float EA = fmaf(eP, vA, eA);     // thread-exit map: x -> EA + EP*x
  const float EP = eP * vP;

  // per-thread contributions to segment moments (alpha = a + p*EA, pi = p*EP)
  float ca  = fmaf(EA, sp, sa);
  float cp  = EP * sp;
  float caa = fmaf(EA, fmaf(2.f, sap, EA * spp), saa);
  float cap = EP * fmaf(EA, spp, sap);
  float cpp = EP * EP * spp;

#pragma unroll
  for (int d = 32; d >= 1; d >>= 1) {
    ca  += __shfl_down(ca, d);
    cp  += __shfl_down(cp, d);
    caa += __shfl_down(caa, d);
    cap += __shfl_down(cap, d);
    cpp += __shfl_down(cpp, d);
  }
  if (lane == 0) {
    red[wv] = ca; red[4 + wv] = cp; red[8 + wv] = caa;
    red[12 + wv] = cap; red[16 + wv] = cpp;
  }
  __syncthreads();
  if (tid == 0) {
    fSa[blk]  = red[0]  + red[1]  + red[2]  + red[3];
    fSp[blk]  = red[4]  + red[5]  + red[6]  + red[7];
    fSaa[blk] = red[8]  + red[9]  + red[10] + red[11];
    fSap[blk] = red[12] + red[13] + red[14] + red[15];
    fSpp[blk] = red[16] + red[17] + red[18] + red[19];
    float gA = 0.f, gP = 1.f;
#pragma unroll
    for (int j = 3; j >= 0; --j) { gA = fmaf(wgP[j], gA, wgA[j]); gP *= wgP[j]; }
    fA[blk] = gA; fP[blk] = gP;
  }
}

// ---------------------------------------------------------------------------
// K_M: single block. Per row: chain the 8 segment composites -> per-segment
// carries, row sum/sumsq -> rowInv; block-reduce row sums -> global mean.
// ---------------------------------------------------------------------------
__global__ __launch_bounds__(256) void er_mid(const float* __restrict__ fA,  const float* __restrict__ fP,
                                              const float* __restrict__ fSa, const float* __restrict__ fSp,
                                              const float* __restrict__ fSaa,const float* __restrict__ fSap,
                                              const float* __restrict__ fSpp,
                                              float* __restrict__ cArr,
                                              float* __restrict__ rowInv,
                                              float* __restrict__ meanPtr) {
  const int tid = threadIdx.x;
  double tsum = 0.0;
  for (int i = 0; i < BROWS / 256; ++i) {
    const int r  = tid + 256 * i;
    const int b0 = r * NSEG;
    float A[NSEG], P[NSEG], Sa[NSEG], Sp[NSEG], Saa[NSEG], Sap[NSEG], Spp[NSEG];
#pragma unroll
    for (int h = 0; h < 2; ++h) {
      *(float4*)(A   + 4*h) = ((const float4*)(fA   + b0))[h];
      *(float4*)(P   + 4*h) = ((const float4*)(fP   + b0))[h];
      *(float4*)(Sa  + 4*h) = ((const float4*)(fSa  + b0))[h];
      *(float4*)(Sp  + 4*h) = ((const float4*)(fSp  + b0))[h];
      *(float4*)(Saa + 4*h) = ((const float4*)(fSaa + b0))[h];
      *(float4*)(Sap + 4*h) = ((const float4*)(fSap + b0))[h];
      *(float4*)(Spp + 4*h) = ((const float4*)(fSpp + b0))[h];
    }
    float c[NSEG];
    float v = 0.f;
#pragma unroll
    for (int s = NSEG - 1; s >= 0; --s) { c[s] = v; v = fmaf(P[s], v, A[s]); }

    double rs = 0.0, rq = 0.0;
#pragma unroll
    for (int s = 0; s < NSEG; ++s) {
      rs += (double)fmaf(Sp[s], c[s], Sa[s]);
      rq += (double)fmaf(c[s], fmaf(2.f, Sap[s], c[s] * Spp[s]), Saa[s]);
    }
#pragma unroll
    for (int h = 0; h < 2; ++h)
      ((float4*)(cArr + b0))[h] = *(const float4*)(c + 4*h);

    double var = (rq - rs * rs / (double)TLEN) / (double)(TLEN - 1);
    if (var < 0.0) var = 0.0;
    rowInv[r] = (float)(1.0 / (sqrt(var) + EPSN));
    tsum += rs;
  }
  // block reduction of tsum (double)
#pragma unroll
  for (int d = 32; d >= 1; d >>= 1) tsum += __shfl_down(tsum, d);
  __shared__ double dred[4];
  const int lane = tid & 63, wv = tid >> 6;
  if (lane == 0) dred[wv] = tsum;
  __syncthreads();
  if (tid == 0) {
    const double t = dred[0] + dred[1] + dred[2] + dred[3];
    *meanPtr = (float)(t / ((double)BROWS * (double)TLEN));
  }
}

// ---------------------------------------------------------------------------
// K_B: recompute returns per segment with the known incoming carry, fused
// normalize, fully coalesced float4 store.
// ---------------------------------------------------------------------------
__global__ __launch_bounds__(NT) void er_segB(const float* __restrict__ rew,
                                              const float* __restrict__ don,
                                              const float* __restrict__ cArr,
                                              const float* __restrict__ rowInv,
                                              const float* __restrict__ meanPtr,
                                              float* __restrict__ out) {
  const int blk  = blockIdx.x;
  const int tid  = threadIdx.x;
  const int lane = tid & 63, wv = tid >> 6;
  const size_t base = (size_t)blk * SEG + (size_t)tid * CH;

  const float4 rv = *(const float4*)(rew + base);
  const float4 dv = *(const float4*)(don + base);

  float a[CH], p[CH];
  float A = 0.f, P = 1.f;
  {
    const float r[CH] = {rv.x, rv.y, rv.z, rv.w};
    const float d[CH] = {dv.x, dv.y, dv.z, dv.w};
#pragma unroll
    for (int j = CH - 1; j >= 0; --j) {
      const float c = GAMMA - GAMMA * d[j];
      A = fmaf(c, A, r[j]);
      P *= c;
      a[j] = A; p[j] = P;
    }
  }
  float sA = A, sP = P;
#pragma unroll
  for (int d = 1; d < 64; d <<= 1) {
    const float tA = __shfl_down(sA, d);
    const float tP = __shfl_down(sP, d);
    if (lane + d < 64) { sA = fmaf(sP, tA, sA); sP *= tP; }
  }
  __shared__ float wgA[4], wgP[4];
  if (lane == 0) { wgA[wv] = sA; wgP[wv] = sP; }
  __syncthreads();

  float vA = 0.f, vP = 1.f;
#pragma unroll
  for (int j = 3; j >= 1; --j) {
    const float nA = fmaf(wgP[j], vA, wgA[j]);
    const float nP = vP * wgP[j];
    if (j > wv) { vA = nA; vP = nP; }
  }
  float eA = __shfl_down(sA, 1);
  float eP = __shfl_down(sP, 1);
  if (lane == 63) { eA = 0.f; eP = 1.f; }
  const float EA = fmaf(eP, vA, eA);
  const float EP = eP * vP;

  const float cs    = cArr[blk];
  const float carry = fmaf(EP, cs, EA);   // carry entering this thread's chunk
  const float mean  = *meanPtr;
  const float inv   = rowInv[blk >> 3];   // NSEG segments per row

  float4 o;
  o.x = (fmaf(p[0], carry, a[0]) - mean) * inv;
  o.y = (fmaf(p[1], carry, a[1]) - mean) * inv;
  o.z = (fmaf(p[2], carry, a[2]) - mean) * inv;
  o.w = (fmaf(p[3], carry, a[3]) - mean) * inv;
  *(float4*)(out + base) = o;
}

extern "C" void kernel_launch(void* const* d_in, const int* in_sizes, int n_in,
                              void* d_out, int out_size, void* d_ws, size_t ws_size,
                              hipStream_t stream) {
  const float* rew = (const float*)d_in[0];
  const float* don = (const float*)d_in[1];
  float* out = (float*)d_out;

  float* w      = (float*)d_ws;
  float* fA     = w + 0 * NBLK;
  float* fP     = w + 1 * NBLK;
  float* fSa    = w + 2 * NBLK;
  float* fSp    = w + 3 * NBLK;
  float* fSaa   = w + 4 * NBLK;
  float* fSap   = w + 5 * NBLK;
  float* fSpp   = w + 6 * NBLK;
  float* cArr   = w + 7 * NBLK;
  float* rowInv = w + 8 * NBLK;
  float* meanPtr= w + 8 * NBLK + BROWS;

  er_segA<<<NBLK, NT, 0, stream>>>(rew, don, fA, fP, fSa, fSp, fSaa, fSap, fSpp);
  er_mid<<<1, 256, 0, stream>>>(fA, fP, fSa, fSp, fSaa, fSap, fSpp, cArr, rowInv, meanPtr);
  er_segB<<<NBLK, NT, 0, stream>>>(rew, don, cArr, rowInv, meanPtr, out);
}